// Round 5
// baseline (1131.672 us; speedup 1.0000x reference)
//
#include <hip/hip_runtime.h>
#include <hip/hip_bf16.h>

// GCN on MI355X.
// R4 restructure: exact-CSR build abandoned (R3 showed scattered 4B stores
// cost a full line of downstream write traffic each: WRITE_SIZE 174MB for a
// 12.8MB logical scatter, independent of XCD partitioning). Aggregation only
// needs grouping by 256-node dst range, not sorted CSR:
//   bin_k:  append-only binning, LDS-staged -> contiguous >=192B chunk writes
//   deg_k:  per-range degree count from bins -> dinv
//   aggL1/aggL2: edge-centric scatter into LDS accumulators (ds_add_f32),
//                fused epilogues (bias+relu+W2 | bias+relu+MLP head).
// No float global atomics anywhere; all global writes dense.
// R5: resubmit of R4 (bench infra timeout, kernel never ran).

#define NNODES 100000
#define NEDGES 3200000
#define NR 391           // ceil(100000/256): 256-node dst ranges
#define BSLOT 9216       // per-range edge buffer (mean 8192, +11 sigma)
#define CAP 80           // LDS bin capacity (entries)
#define THRESH 48        // flush threshold (>=192B contiguous chunks)
#define BIN_BLOCKS 128
#define BIN_THREADS 512

// ---------------- binning ----------------
__global__ __launch_bounds__(BIN_THREADS) void bin_k(
    const int* __restrict__ src, const int* __restrict__ dst,
    int* __restrict__ gcur, unsigned int* __restrict__ ebuf) {
  __shared__ unsigned int bins[NR * CAP];   // 125 KB
  __shared__ int bcnt[NR];
  const int tid = threadIdx.x;
  for (int k = tid; k < NR; k += BIN_THREADS) bcnt[k] = 0;
  __syncthreads();

  const int chunk = NEDGES / BIN_BLOCKS;    // 25000 exactly
  int e = blockIdx.x * chunk + tid;
  const int end = blockIdx.x * chunk + chunk;

  bool have = false;
  unsigned int pk = 0;
  int r = 0;
  const int wid = tid >> 6, lane = tid & 63;
  const int nwaves = BIN_THREADS / 64;

  for (;;) {
    // place at most one edge per thread per round (retry on bin overflow)
    if (!have && e < end) {
      int s = src[e], d = dst[e];
      pk = ((unsigned int)s << 8) | (unsigned int)(d & 255);
      r = d >> 8;
      have = true;
      e += BIN_THREADS;
    }
    if (have) {
      int p = atomicAdd(&bcnt[r], 1);
      if (p < CAP) { bins[r * CAP + p] = pk; have = false; }
      else atomicSub(&bcnt[r], 1);          // full: retry after flush
    }
    int active = __syncthreads_count((int)(have || e < end));
    int th = (active == 0) ? 1 : THRESH;
    // flush: each wave owns bins wid, wid+8, ... (no cross-wave races)
    for (int b = wid; b < NR; b += nwaves) {
      int n = bcnt[b];
      if (n >= th) {
        int gp = 0;
        if (lane == 0) gp = atomicAdd(&gcur[b], n);
        gp = __shfl(gp, 0);
        unsigned int* dp = ebuf + (size_t)b * BSLOT + gp;
        for (int k = lane; k < n; k += 64) dp[k] = bins[b * CAP + k];
        if (lane == 0) bcnt[b] = 0;
      }
    }
    __syncthreads();
    if (active == 0) break;
  }
}

// ---------------- degree -> dinv ----------------
__global__ __launch_bounds__(256) void deg_k(
    const int* __restrict__ gcur, const unsigned int* __restrict__ ebuf,
    float* __restrict__ dinv) {
  __shared__ int cnt[256];
  const int r = blockIdx.x, tid = threadIdx.x;
  cnt[tid] = 0;
  __syncthreads();
  const int n = gcur[r];
  const unsigned int* bp = ebuf + (size_t)r * BSLOT;
  for (int k = tid; k < n; k += 256) atomicAdd(&cnt[bp[k] & 255u], 1);
  __syncthreads();
  int i = r * 256 + tid;
  if (i < NNODES) dinv[i] = rsqrtf((float)cnt[tid] + 1.0f);
}

// ---------------- x @ W1 ----------------
__global__ __launch_bounds__(256) void gemm1_k(const float* __restrict__ x,
                                               const float* __restrict__ W,
                                               float* __restrict__ out) {
  __shared__ float w[2048];
  for (int j = threadIdx.x; j < 2048; j += 256) w[j] = W[j];
  __syncthreads();
  int i = blockIdx.x * 256 + threadIdx.x;
  if (i >= NNODES) return;
  float acc[16];
#pragma unroll
  for (int c = 0; c < 16; c++) acc[c] = 0.f;
  const float4* xr = (const float4*)(x + (size_t)i * 128);
#pragma unroll 8
  for (int k4 = 0; k4 < 32; k4++) {
    float4 xv = xr[k4];
    const float* wr = &w[k4 * 64];
#pragma unroll
    for (int c = 0; c < 16; c++)
      acc[c] = fmaf(xv.x, wr[c],
               fmaf(xv.y, wr[16 + c],
               fmaf(xv.z, wr[32 + c],
               fmaf(xv.w, wr[48 + c], acc[c]))));
  }
  float4* op = (float4*)(out + (size_t)i * 16);
  op[0] = make_float4(acc[0], acc[1], acc[2], acc[3]);
  op[1] = make_float4(acc[4], acc[5], acc[6], acc[7]);
  op[2] = make_float4(acc[8], acc[9], acc[10], acc[11]);
  op[3] = make_float4(acc[12], acc[13], acc[14], acc[15]);
}

__device__ __forceinline__ void load_row(const float* __restrict__ h, int s,
                                         float v[16]) {
  const float4* hr = (const float4*)(h + (size_t)s * 16);
  *(float4*)&v[0]  = hr[0];
  *(float4*)&v[4]  = hr[1];
  *(float4*)&v[8]  = hr[2];
  *(float4*)&v[12] = hr[3];
}

// ---------------- layer 1: agg + b1 + relu + @W2 ----------------
__global__ __launch_bounds__(256) void aggL1_k(
    const float* __restrict__ h, const int* __restrict__ gcur,
    const unsigned int* __restrict__ ebuf, const float* __restrict__ dinv,
    const float* __restrict__ b1, const float* __restrict__ W2,
    float* __restrict__ out) {
  __shared__ float acc[256 * 17];   // stride 17: conflict-free random-row ds_add
  __shared__ float w2[256];
  __shared__ float bb[16];
  const int r = blockIdx.x, tid = threadIdx.x;
  for (int k = tid; k < 256 * 17; k += 256) acc[k] = 0.f;
  w2[tid] = W2[tid];
  if (tid < 16) bb[tid] = b1[tid];
  __syncthreads();
  const int n = gcur[r];
  const unsigned int* bp = ebuf + (size_t)r * BSLOT;
  for (int k = tid; k < n; k += 256) {
    unsigned int pk = bp[k];
    int s = (int)(pk >> 8);
    int dl = (int)(pk & 255u);
    float w = dinv[s];
    float hv[16];
    load_row(h, s, hv);
    float* ap = &acc[dl * 17];
#pragma unroll
    for (int c = 0; c < 16; c++) atomicAdd(&ap[c], w * hv[c]);
  }
  __syncthreads();
  int i = r * 256 + tid;
  if (i >= NNODES) return;
  float di = dinv[i], d2 = di * di;
  float hv[16];
  load_row(h, i, hv);
  float a[16];
#pragma unroll
  for (int c = 0; c < 16; c++)
    a[c] = fmaxf(fmaf(di, acc[tid * 17 + c], fmaf(d2, hv[c], bb[c])), 0.f);
  float o[16];
#pragma unroll
  for (int c = 0; c < 16; c++) o[c] = 0.f;
#pragma unroll
  for (int k = 0; k < 16; k++) {
    float ak = a[k];
#pragma unroll
    for (int c = 0; c < 16; c++) o[c] = fmaf(ak, w2[k * 16 + c], o[c]);
  }
  float4* op = (float4*)(out + (size_t)i * 16);
  op[0] = *(float4*)&o[0];
  op[1] = *(float4*)&o[4];
  op[2] = *(float4*)&o[8];
  op[3] = *(float4*)&o[12];
}

// ---------------- layer 2: agg + b2 + relu + MLP head ----------------
__global__ __launch_bounds__(256) void aggL2_k(
    const float* __restrict__ h, const int* __restrict__ gcur,
    const unsigned int* __restrict__ ebuf, const float* __restrict__ dinv,
    const float* __restrict__ b2, const float* __restrict__ l1w,
    const float* __restrict__ l1b, const float* __restrict__ l2w,
    const float* __restrict__ l2b, float* __restrict__ out) {
  __shared__ float acc[256 * 17];
  __shared__ float w1[256];
  __shared__ float bb[16], bb1[16], w2s[16];
  __shared__ float bb2;
  const int r = blockIdx.x, tid = threadIdx.x;
  for (int k = tid; k < 256 * 17; k += 256) acc[k] = 0.f;
  w1[tid] = l1w[tid];
  if (tid < 16) bb[tid] = b2[tid];
  if (tid >= 16 && tid < 32) bb1[tid - 16] = l1b[tid - 16];
  if (tid >= 32 && tid < 48) w2s[tid - 32] = l2w[tid - 32];
  if (tid == 48) bb2 = l2b[0];
  __syncthreads();
  const int n = gcur[r];
  const unsigned int* bp = ebuf + (size_t)r * BSLOT;
  for (int k = tid; k < n; k += 256) {
    unsigned int pk = bp[k];
    int s = (int)(pk >> 8);
    int dl = (int)(pk & 255u);
    float w = dinv[s];
    float hv[16];
    load_row(h, s, hv);
    float* ap = &acc[dl * 17];
#pragma unroll
    for (int c = 0; c < 16; c++) atomicAdd(&ap[c], w * hv[c]);
  }
  __syncthreads();
  int i = r * 256 + tid;
  if (i >= NNODES) return;
  float di = dinv[i], d2 = di * di;
  float hv[16];
  load_row(h, i, hv);
  float a[16];
#pragma unroll
  for (int c = 0; c < 16; c++)
    a[c] = fmaxf(fmaf(di, acc[tid * 17 + c], fmaf(d2, hv[c], bb[c])), 0.f);
  float o = bb2;
#pragma unroll
  for (int j = 0; j < 16; j++) {
    float s = bb1[j];
#pragma unroll
    for (int k = 0; k < 16; k++) s = fmaf(a[k], w1[k * 16 + j], s);
    o = fmaf(fmaxf(s, 0.f), w2s[j], o);
  }
  out[i] = o;
}

extern "C" void kernel_launch(void* const* d_in, const int* in_sizes, int n_in,
                              void* d_out, int out_size, void* d_ws, size_t ws_size,
                              hipStream_t stream) {
  const float* x   = (const float*)d_in[0];
  const int*   ei  = (const int*)d_in[1];
  const float* W1  = (const float*)d_in[2];
  const float* b1  = (const float*)d_in[3];
  const float* W2  = (const float*)d_in[4];
  const float* b2  = (const float*)d_in[5];
  const float* l1w = (const float*)d_in[6];
  const float* l1b = (const float*)d_in[7];
  const float* l2w = (const float*)d_in[8];
  const float* l2b = (const float*)d_in[9];
  float* out = (float*)d_out;

  char* ws = (char*)d_ws;
  size_t off = 0;
  auto alloc = [&](size_t bytes) {
    size_t o = off;
    off += (bytes + 255) & ~(size_t)255;
    return o;
  };
  int*          gcur = (int*)(ws + alloc((size_t)NR * 4));
  float*        dinv = (float*)(ws + alloc((size_t)NNODES * 4));
  unsigned int* ebuf = (unsigned int*)(ws + alloc((size_t)NR * BSLOT * 4));
  float*        buf0 = (float*)(ws + alloc((size_t)NNODES * 16 * 4));
  float*        buf1 = (float*)(ws + alloc((size_t)NNODES * 16 * 4));

  const int* srcv = ei;
  const int* dstv = ei + NEDGES;
  const int NB_N = (NNODES + 255) / 256;  // 391

  hipMemsetAsync(gcur, 0, (size_t)NR * 4, stream);
  bin_k<<<BIN_BLOCKS, BIN_THREADS, 0, stream>>>(srcv, dstv, gcur, ebuf);
  deg_k<<<NR, 256, 0, stream>>>(gcur, ebuf, dinv);
  gemm1_k<<<NB_N, 256, 0, stream>>>(x, W1, buf0);
  aggL1_k<<<NR, 256, 0, stream>>>(buf0, gcur, ebuf, dinv, b1, W2, buf1);
  aggL2_k<<<NR, 256, 0, stream>>>(buf1, gcur, ebuf, dinv, b2,
                                  l1w, l1b, l2w, l2b, out);
}

// Round 7
// 1096.108 us; speedup vs baseline: 1.0324x; 1.0324x over previous
//
#include <hip/hip_runtime.h>
#include <hip/hip_bf16.h>

// GCN on MI355X. Binned edges (256-node dst ranges) + LDS-accumulator agg.
// R5 post-mortem: agg was random-gather latency-bound (occupancy 13%, VALU 1%,
// 300 GB/s effective). R6: P=4 sub-blocks per range (4x occupancy), 4 lanes
// per edge + 2-edge batching (per-lane chain: 2 indep float4 gathers + 8
// fire-and-forget ds_adds), dense partial buffers + fused reduce epilogues.
// R7: resubmit of R6 (broker timeout, kernel never ran). ws use ~53 MB.

#define NNODES 100000
#define NEDGES 3200000
#define NR 391           // ceil(100000/256): 256-node dst ranges
#define BSLOT 9216       // per-range edge buffer (mean 8192, +11 sigma)
#define CAP 80           // LDS bin capacity (entries)
#define THRESH 48        // flush threshold (>=192B contiguous chunks)
#define BIN_BLOCKS 256
#define BIN_THREADS 512
#define P 4              // agg sub-blocks per range

// ---------------- binning ----------------
__global__ __launch_bounds__(BIN_THREADS) void bin_k(
    const int* __restrict__ src, const int* __restrict__ dst,
    int* __restrict__ gcur, unsigned int* __restrict__ ebuf) {
  __shared__ unsigned int bins[NR * CAP];   // 125 KB
  __shared__ int bcnt[NR];
  const int tid = threadIdx.x;
  for (int k = tid; k < NR; k += BIN_THREADS) bcnt[k] = 0;
  __syncthreads();

  const int chunk = NEDGES / BIN_BLOCKS;    // 12500 exactly
  int e = blockIdx.x * chunk + tid;
  const int end = blockIdx.x * chunk + chunk;

  bool have = false;
  unsigned int pk = 0;
  int r = 0;
  const int wid = tid >> 6, lane = tid & 63;
  const int nwaves = BIN_THREADS / 64;

  for (;;) {
    if (!have && e < end) {
      int s = src[e], d = dst[e];
      pk = ((unsigned int)s << 8) | (unsigned int)(d & 255);
      r = d >> 8;
      have = true;
      e += BIN_THREADS;
    }
    if (have) {
      int p = atomicAdd(&bcnt[r], 1);
      if (p < CAP) { bins[r * CAP + p] = pk; have = false; }
      else atomicSub(&bcnt[r], 1);          // full: retry after flush
    }
    int active = __syncthreads_count((int)(have || e < end));
    int th = (active == 0) ? 1 : THRESH;
    for (int b = wid; b < NR; b += nwaves) {
      int n = bcnt[b];
      if (n >= th) {
        int gp = 0;
        if (lane == 0) gp = atomicAdd(&gcur[b], n);
        gp = __shfl(gp, 0);
        unsigned int* dp = ebuf + (size_t)b * BSLOT + gp;
        for (int k = lane; k < n; k += 64) dp[k] = bins[b * CAP + k];
        if (lane == 0) bcnt[b] = 0;
      }
    }
    __syncthreads();
    if (active == 0) break;
  }
}

// ---------------- degree -> dinv ----------------
__global__ __launch_bounds__(256) void deg_k(
    const int* __restrict__ gcur, const unsigned int* __restrict__ ebuf,
    float* __restrict__ dinv) {
  __shared__ int cnt[256];
  const int r = blockIdx.x, tid = threadIdx.x;
  cnt[tid] = 0;
  __syncthreads();
  const int n = gcur[r];
  const unsigned int* bp = ebuf + (size_t)r * BSLOT;
  for (int k = tid; k < n; k += 256) atomicAdd(&cnt[bp[k] & 255u], 1);
  __syncthreads();
  int i = r * 256 + tid;
  if (i < NNODES) dinv[i] = rsqrtf((float)cnt[tid] + 1.0f);
}

// ---------------- x @ W1 ----------------
__global__ __launch_bounds__(256) void gemm1_k(const float* __restrict__ x,
                                               const float* __restrict__ W,
                                               float* __restrict__ out) {
  __shared__ float w[2048];
  for (int j = threadIdx.x; j < 2048; j += 256) w[j] = W[j];
  __syncthreads();
  int i = blockIdx.x * 256 + threadIdx.x;
  if (i >= NNODES) return;
  float acc[16];
#pragma unroll
  for (int c = 0; c < 16; c++) acc[c] = 0.f;
  const float4* xr = (const float4*)(x + (size_t)i * 128);
#pragma unroll 8
  for (int k4 = 0; k4 < 32; k4++) {
    float4 xv = xr[k4];
    const float* wr = &w[k4 * 64];
#pragma unroll
    for (int c = 0; c < 16; c++)
      acc[c] = fmaf(xv.x, wr[c],
               fmaf(xv.y, wr[16 + c],
               fmaf(xv.z, wr[32 + c],
               fmaf(xv.w, wr[48 + c], acc[c]))));
  }
  float4* op = (float4*)(out + (size_t)i * 16);
  op[0] = make_float4(acc[0], acc[1], acc[2], acc[3]);
  op[1] = make_float4(acc[4], acc[5], acc[6], acc[7]);
  op[2] = make_float4(acc[8], acc[9], acc[10], acc[11]);
  op[3] = make_float4(acc[12], acc[13], acc[14], acc[15]);
}

__device__ __forceinline__ void load_row(const float* __restrict__ h, int s,
                                         float v[16]) {
  const float4* hr = (const float4*)(h + (size_t)s * 16);
  *(float4*)&v[0]  = hr[0];
  *(float4*)&v[4]  = hr[1];
  *(float4*)&v[8]  = hr[2];
  *(float4*)&v[12] = hr[3];
}

// ---------------- partial aggregation (P sub-blocks per range) ----------------
// Block (r,p) processes slice [n*p/P, n*(p+1)/P) of bin r.
// 4 lanes per edge, each lane handles 4 channels; 2 edges per iteration.
__global__ __launch_bounds__(256) void aggP_k(
    const float* __restrict__ h, const int* __restrict__ gcur,
    const unsigned int* __restrict__ ebuf, const float* __restrict__ dinv,
    float* __restrict__ partial) {
  __shared__ float acc[256 * 17];   // stride 17: spread banks
  const int r = blockIdx.x >> 2;
  const int p = blockIdx.x & 3;
  const int tid = threadIdx.x;
  for (int k = tid; k < 256 * 17; k += 256) acc[k] = 0.f;
  __syncthreads();
  const int n = gcur[r];
  const int lo = (n * p) >> 2;
  const int hi = (n * (p + 1)) >> 2;
  const unsigned int* bp = ebuf + (size_t)r * BSLOT;
  const int c4 = tid & 3;           // channel quad owned by this lane
  int k = lo + (tid >> 2);
  for (; k + 64 < hi; k += 128) {   // 2 independent edges in flight
    unsigned int pk0 = bp[k];
    unsigned int pk1 = bp[k + 64];
    int s0 = (int)(pk0 >> 8), dl0 = (int)(pk0 & 255u);
    int s1 = (int)(pk1 >> 8), dl1 = (int)(pk1 & 255u);
    float w0 = dinv[s0], w1 = dinv[s1];
    float4 hv0 = ((const float4*)(h + (size_t)s0 * 16))[c4];
    float4 hv1 = ((const float4*)(h + (size_t)s1 * 16))[c4];
    float* a0 = &acc[dl0 * 17 + c4 * 4];
    float* a1 = &acc[dl1 * 17 + c4 * 4];
    atomicAdd(&a0[0], w0 * hv0.x);
    atomicAdd(&a0[1], w0 * hv0.y);
    atomicAdd(&a0[2], w0 * hv0.z);
    atomicAdd(&a0[3], w0 * hv0.w);
    atomicAdd(&a1[0], w1 * hv1.x);
    atomicAdd(&a1[1], w1 * hv1.y);
    atomicAdd(&a1[2], w1 * hv1.z);
    atomicAdd(&a1[3], w1 * hv1.w);
  }
  if (k < hi) {
    unsigned int pk0 = bp[k];
    int s0 = (int)(pk0 >> 8), dl0 = (int)(pk0 & 255u);
    float w0 = dinv[s0];
    float4 hv0 = ((const float4*)(h + (size_t)s0 * 16))[c4];
    float* a0 = &acc[dl0 * 17 + c4 * 4];
    atomicAdd(&a0[0], w0 * hv0.x);
    atomicAdd(&a0[1], w0 * hv0.y);
    atomicAdd(&a0[2], w0 * hv0.z);
    atomicAdd(&a0[3], w0 * hv0.w);
  }
  __syncthreads();
  float v[16];
#pragma unroll
  for (int c = 0; c < 16; c++) v[c] = acc[tid * 17 + c];
  float4* pp = (float4*)(partial + (((size_t)p * NR + r) * 256 + tid) * 16);
  pp[0] = *(float4*)&v[0];
  pp[1] = *(float4*)&v[4];
  pp[2] = *(float4*)&v[8];
  pp[3] = *(float4*)&v[12];
}

// ---------------- reduce + self-loop + b1 + relu + @W2 ----------------
__global__ __launch_bounds__(256) void redL1_k(
    const float* __restrict__ partial, const float* __restrict__ h,
    const float* __restrict__ dinv, const float* __restrict__ b1,
    const float* __restrict__ W2, float* __restrict__ out) {
  __shared__ float w2[256];
  __shared__ float bb[16];
  const int r = blockIdx.x, tid = threadIdx.x;
  w2[tid] = W2[tid];
  if (tid < 16) bb[tid] = b1[tid];
  __syncthreads();
  float sum[16];
#pragma unroll
  for (int c = 0; c < 16; c++) sum[c] = 0.f;
#pragma unroll
  for (int p = 0; p < P; p++) {
    float pv[16];
    load_row(partial, (p * NR + r) * 256 + tid, pv);
#pragma unroll
    for (int c = 0; c < 16; c++) sum[c] += pv[c];
  }
  const int i = r * 256 + tid;
  if (i >= NNODES) return;
  float di = dinv[i], d2 = di * di;
  float hv[16];
  load_row(h, i, hv);
  float a[16];
#pragma unroll
  for (int c = 0; c < 16; c++)
    a[c] = fmaxf(fmaf(di, sum[c], fmaf(d2, hv[c], bb[c])), 0.f);
  float o[16];
#pragma unroll
  for (int c = 0; c < 16; c++) o[c] = 0.f;
#pragma unroll
  for (int k = 0; k < 16; k++) {
    float ak = a[k];
#pragma unroll
    for (int c = 0; c < 16; c++) o[c] = fmaf(ak, w2[k * 16 + c], o[c]);
  }
  float4* op = (float4*)(out + (size_t)i * 16);
  op[0] = *(float4*)&o[0];
  op[1] = *(float4*)&o[4];
  op[2] = *(float4*)&o[8];
  op[3] = *(float4*)&o[12];
}

// ---------------- reduce + self-loop + b2 + relu + MLP head ----------------
__global__ __launch_bounds__(256) void redL2_k(
    const float* __restrict__ partial, const float* __restrict__ h,
    const float* __restrict__ dinv, const float* __restrict__ b2,
    const float* __restrict__ l1w, const float* __restrict__ l1b,
    const float* __restrict__ l2w, const float* __restrict__ l2b,
    float* __restrict__ out) {
  __shared__ float w1[256];
  __shared__ float bb[16], bb1[16], w2s[16];
  __shared__ float bb2;
  const int r = blockIdx.x, tid = threadIdx.x;
  w1[tid] = l1w[tid];
  if (tid < 16) bb[tid] = b2[tid];
  if (tid >= 16 && tid < 32) bb1[tid - 16] = l1b[tid - 16];
  if (tid >= 32 && tid < 48) w2s[tid - 32] = l2w[tid - 32];
  if (tid == 48) bb2 = l2b[0];
  __syncthreads();
  float sum[16];
#pragma unroll
  for (int c = 0; c < 16; c++) sum[c] = 0.f;
#pragma unroll
  for (int p = 0; p < P; p++) {
    float pv[16];
    load_row(partial, (p * NR + r) * 256 + tid, pv);
#pragma unroll
    for (int c = 0; c < 16; c++) sum[c] += pv[c];
  }
  const int i = r * 256 + tid;
  if (i >= NNODES) return;
  float di = dinv[i], d2 = di * di;
  float hv[16];
  load_row(h, i, hv);
  float a[16];
#pragma unroll
  for (int c = 0; c < 16; c++)
    a[c] = fmaxf(fmaf(di, sum[c], fmaf(d2, hv[c], bb[c])), 0.f);
  float o = bb2;
#pragma unroll
  for (int j = 0; j < 16; j++) {
    float s = bb1[j];
#pragma unroll
    for (int k = 0; k < 16; k++) s = fmaf(a[k], w1[k * 16 + j], s);
    o = fmaf(fmaxf(s, 0.f), w2s[j], o);
  }
  out[i] = o;
}

extern "C" void kernel_launch(void* const* d_in, const int* in_sizes, int n_in,
                              void* d_out, int out_size, void* d_ws, size_t ws_size,
                              hipStream_t stream) {
  const float* x   = (const float*)d_in[0];
  const int*   ei  = (const int*)d_in[1];
  const float* W1  = (const float*)d_in[2];
  const float* b1  = (const float*)d_in[3];
  const float* W2  = (const float*)d_in[4];
  const float* b2  = (const float*)d_in[5];
  const float* l1w = (const float*)d_in[6];
  const float* l1b = (const float*)d_in[7];
  const float* l2w = (const float*)d_in[8];
  const float* l2b = (const float*)d_in[9];
  float* out = (float*)d_out;

  char* ws = (char*)d_ws;
  size_t off = 0;
  auto alloc = [&](size_t bytes) {
    size_t o = off;
    off += (bytes + 255) & ~(size_t)255;
    return o;
  };
  int*          gcur    = (int*)(ws + alloc((size_t)NR * 4));
  float*        dinv    = (float*)(ws + alloc((size_t)NNODES * 4));
  unsigned int* ebuf    = (unsigned int*)(ws + alloc((size_t)NR * BSLOT * 4));
  float*        buf0    = (float*)(ws + alloc((size_t)NNODES * 16 * 4));
  float*        buf1    = (float*)(ws + alloc((size_t)NNODES * 16 * 4));
  float*        partial = (float*)(ws + alloc((size_t)P * NR * 256 * 16 * 4));

  const int* srcv = ei;
  const int* dstv = ei + NEDGES;
  const int NB_N = (NNODES + 255) / 256;  // 391

  hipMemsetAsync(gcur, 0, (size_t)NR * 4, stream);
  bin_k<<<BIN_BLOCKS, BIN_THREADS, 0, stream>>>(srcv, dstv, gcur, ebuf);
  deg_k<<<NR, 256, 0, stream>>>(gcur, ebuf, dinv);
  gemm1_k<<<NB_N, 256, 0, stream>>>(x, W1, buf0);
  aggP_k<<<NR * P, 256, 0, stream>>>(buf0, gcur, ebuf, dinv, partial);
  redL1_k<<<NR, 256, 0, stream>>>(partial, buf0, dinv, b1, W2, buf1);
  aggP_k<<<NR * P, 256, 0, stream>>>(buf1, gcur, ebuf, dinv, partial);
  redL2_k<<<NR, 256, 0, stream>>>(partial, buf1, dinv, b2,
                                  l1w, l1b, l2w, l2b, out);
}

// Round 13
// 773.036 us; speedup vs baseline: 1.4639x; 1.4179x over previous
//
#include <hip/hip_runtime.h>
#include <hip/hip_bf16.h>

// GCN on MI355X. Edge binning by 256-node dst range + LDS-accumulator agg.
// R7 post-mortem: bin_k (streaming retry loop) = 400us, latency-serialized
// (21% occ, 25 rounds x full bin scan + barriers). R8: replace with per-block
// counting sort of an 8192-edge chunk: histogram -> scan -> LDS place ->
// contiguous copy-out; one global atomic per (chunk,range). 5 barriers total.
// aggP (P=4 sub-blocks/range, 4 lanes/edge, 2-edge ILP) + fused reduces kept.
// R13: resubmit of R8 (5 infra failures in a row; kernel never executed).
// ws use ~53.3 MB — same allocation map as R7's successful run.

#define NNODES 100000
#define NEDGES 3200000
#define NR 391           // ceil(100000/256): 256-node dst ranges
#define BSLOT 9216       // per-range edge buffer (mean 8192, +11 sigma)
#define CHUNK 8192       // edges per sort block
#define NCHUNK ((NEDGES + CHUNK - 1) / CHUNK)  // 391
#define P 4              // agg sub-blocks per range

// ---------------- chunked counting-sort binning ----------------
__global__ __launch_bounds__(512) void sortbin_k(
    const int* __restrict__ src, const int* __restrict__ dst,
    int* __restrict__ gcur, unsigned int* __restrict__ ebuf) {
  __shared__ unsigned int stage[CHUNK];             // 32 KB
  __shared__ int cnt[NR], off0[NR], cur[NR], gb[NR];
  __shared__ int sc[512];
  const int tid = threadIdx.x;
  const int e0 = blockIdx.x * CHUNK;
  const int n = min(CHUNK, NEDGES - e0);
  for (int k = tid; k < NR; k += 512) cnt[k] = 0;
  __syncthreads();
  // phase 1: per-range histogram
  for (int k = tid; k < n; k += 512)
    atomicAdd(&cnt[dst[e0 + k] >> 8], 1);
  __syncthreads();
  // phase 2: exclusive scan (Hillis-Steele over 512-padded)
  sc[tid] = (tid < NR) ? cnt[tid] : 0;
  __syncthreads();
  for (int o = 1; o < 512; o <<= 1) {
    int x = (tid >= o) ? sc[tid - o] : 0;
    __syncthreads();
    sc[tid] += x;
    __syncthreads();
  }
  if (tid < NR) {
    int e = sc[tid] - cnt[tid];
    off0[tid] = e;
    cur[tid] = e;
    gb[tid] = (cnt[tid] > 0) ? atomicAdd(&gcur[tid], cnt[tid]) : 0;
  }
  __syncthreads();
  // phase 3: place into LDS at exact local offset (re-read is L2-hot)
  for (int k = tid; k < n; k += 512) {
    int s = src[e0 + k], d = dst[e0 + k];
    unsigned int pk = ((unsigned int)s << 8) | (unsigned int)(d & 255);
    int p = atomicAdd(&cur[d >> 8], 1);
    stage[p] = pk;
  }
  __syncthreads();
  // phase 4: copy each range's segment to its global slot (dense writes)
  const int wid = tid >> 6, lane = tid & 63;
  for (int r = wid; r < NR; r += 8) {
    int m = cnt[r];
    if (m == 0) continue;
    unsigned int* dp = ebuf + (size_t)r * BSLOT + gb[r];
    const unsigned int* sp = &stage[off0[r]];
    for (int k = lane; k < m; k += 64) dp[k] = sp[k];
  }
}

// ---------------- degree -> dinv ----------------
__global__ __launch_bounds__(256) void deg_k(
    const int* __restrict__ gcur, const unsigned int* __restrict__ ebuf,
    float* __restrict__ dinv) {
  __shared__ int cnt[256];
  const int r = blockIdx.x, tid = threadIdx.x;
  cnt[tid] = 0;
  __syncthreads();
  const int n = gcur[r];
  const unsigned int* bp = ebuf + (size_t)r * BSLOT;
  for (int k = tid; k < n; k += 256) atomicAdd(&cnt[bp[k] & 255u], 1);
  __syncthreads();
  int i = r * 256 + tid;
  if (i < NNODES) dinv[i] = rsqrtf((float)cnt[tid] + 1.0f);
}

// ---------------- x @ W1 ----------------
__global__ __launch_bounds__(256) void gemm1_k(const float* __restrict__ x,
                                               const float* __restrict__ W,
                                               float* __restrict__ out) {
  __shared__ float w[2048];
  for (int j = threadIdx.x; j < 2048; j += 256) w[j] = W[j];
  __syncthreads();
  int i = blockIdx.x * 256 + threadIdx.x;
  if (i >= NNODES) return;
  float acc[16];
#pragma unroll
  for (int c = 0; c < 16; c++) acc[c] = 0.f;
  const float4* xr = (const float4*)(x + (size_t)i * 128);
#pragma unroll 8
  for (int k4 = 0; k4 < 32; k4++) {
    float4 xv = xr[k4];
    const float* wr = &w[k4 * 64];
#pragma unroll
    for (int c = 0; c < 16; c++)
      acc[c] = fmaf(xv.x, wr[c],
               fmaf(xv.y, wr[16 + c],
               fmaf(xv.z, wr[32 + c],
               fmaf(xv.w, wr[48 + c], acc[c]))));
  }
  float4* op = (float4*)(out + (size_t)i * 16);
  op[0] = make_float4(acc[0], acc[1], acc[2], acc[3]);
  op[1] = make_float4(acc[4], acc[5], acc[6], acc[7]);
  op[2] = make_float4(acc[8], acc[9], acc[10], acc[11]);
  op[3] = make_float4(acc[12], acc[13], acc[14], acc[15]);
}

__device__ __forceinline__ void load_row(const float* __restrict__ h, int s,
                                         float v[16]) {
  const float4* hr = (const float4*)(h + (size_t)s * 16);
  *(float4*)&v[0]  = hr[0];
  *(float4*)&v[4]  = hr[1];
  *(float4*)&v[8]  = hr[2];
  *(float4*)&v[12] = hr[3];
}

// ---------------- partial aggregation (P sub-blocks per range) ----------------
// Block (r,p) processes slice [n*p/P, n*(p+1)/P) of bin r.
// 4 lanes per edge, each lane handles 4 channels; 2 edges per iteration.
__global__ __launch_bounds__(256) void aggP_k(
    const float* __restrict__ h, const int* __restrict__ gcur,
    const unsigned int* __restrict__ ebuf, const float* __restrict__ dinv,
    float* __restrict__ partial) {
  __shared__ float acc[256 * 17];   // stride 17: spread banks
  const int r = blockIdx.x >> 2;
  const int p = blockIdx.x & 3;
  const int tid = threadIdx.x;
  for (int k = tid; k < 256 * 17; k += 256) acc[k] = 0.f;
  __syncthreads();
  const int n = gcur[r];
  const int lo = (n * p) >> 2;
  const int hi = (n * (p + 1)) >> 2;
  const unsigned int* bp = ebuf + (size_t)r * BSLOT;
  const int c4 = tid & 3;           // channel quad owned by this lane
  int k = lo + (tid >> 2);
  for (; k + 64 < hi; k += 128) {   // 2 independent edges in flight
    unsigned int pk0 = bp[k];
    unsigned int pk1 = bp[k + 64];
    int s0 = (int)(pk0 >> 8), dl0 = (int)(pk0 & 255u);
    int s1 = (int)(pk1 >> 8), dl1 = (int)(pk1 & 255u);
    float w0 = dinv[s0], w1 = dinv[s1];
    float4 hv0 = ((const float4*)(h + (size_t)s0 * 16))[c4];
    float4 hv1 = ((const float4*)(h + (size_t)s1 * 16))[c4];
    float* a0 = &acc[dl0 * 17 + c4 * 4];
    float* a1 = &acc[dl1 * 17 + c4 * 4];
    atomicAdd(&a0[0], w0 * hv0.x);
    atomicAdd(&a0[1], w0 * hv0.y);
    atomicAdd(&a0[2], w0 * hv0.z);
    atomicAdd(&a0[3], w0 * hv0.w);
    atomicAdd(&a1[0], w1 * hv1.x);
    atomicAdd(&a1[1], w1 * hv1.y);
    atomicAdd(&a1[2], w1 * hv1.z);
    atomicAdd(&a1[3], w1 * hv1.w);
  }
  if (k < hi) {
    unsigned int pk0 = bp[k];
    int s0 = (int)(pk0 >> 8), dl0 = (int)(pk0 & 255u);
    float w0 = dinv[s0];
    float4 hv0 = ((const float4*)(h + (size_t)s0 * 16))[c4];
    float* a0 = &acc[dl0 * 17 + c4 * 4];
    atomicAdd(&a0[0], w0 * hv0.x);
    atomicAdd(&a0[1], w0 * hv0.y);
    atomicAdd(&a0[2], w0 * hv0.z);
    atomicAdd(&a0[3], w0 * hv0.w);
  }
  __syncthreads();
  float v[16];
#pragma unroll
  for (int c = 0; c < 16; c++) v[c] = acc[tid * 17 + c];
  float4* pp = (float4*)(partial + (((size_t)p * NR + r) * 256 + tid) * 16);
  pp[0] = *(float4*)&v[0];
  pp[1] = *(float4*)&v[4];
  pp[2] = *(float4*)&v[8];
  pp[3] = *(float4*)&v[12];
}

// ---------------- reduce + self-loop + b1 + relu + @W2 ----------------
__global__ __launch_bounds__(256) void redL1_k(
    const float* __restrict__ partial, const float* __restrict__ h,
    const float* __restrict__ dinv, const float* __restrict__ b1,
    const float* __restrict__ W2, float* __restrict__ out) {
  __shared__ float w2[256];
  __shared__ float bb[16];
  const int r = blockIdx.x, tid = threadIdx.x;
  w2[tid] = W2[tid];
  if (tid < 16) bb[tid] = b1[tid];
  __syncthreads();
  float sum[16];
#pragma unroll
  for (int c = 0; c < 16; c++) sum[c] = 0.f;
#pragma unroll
  for (int p = 0; p < P; p++) {
    float pv[16];
    load_row(partial, (p * NR + r) * 256 + tid, pv);
#pragma unroll
    for (int c = 0; c < 16; c++) sum[c] += pv[c];
  }
  const int i = r * 256 + tid;
  if (i >= NNODES) return;
  float di = dinv[i], d2 = di * di;
  float hv[16];
  load_row(h, i, hv);
  float a[16];
#pragma unroll
  for (int c = 0; c < 16; c++)
    a[c] = fmaxf(fmaf(di, sum[c], fmaf(d2, hv[c], bb[c])), 0.f);
  float o[16];
#pragma unroll
  for (int c = 0; c < 16; c++) o[c] = 0.f;
#pragma unroll
  for (int k = 0; k < 16; k++) {
    float ak = a[k];
#pragma unroll
    for (int c = 0; c < 16; c++) o[c] = fmaf(ak, w2[k * 16 + c], o[c]);
  }
  float4* op = (float4*)(out + (size_t)i * 16);
  op[0] = *(float4*)&o[0];
  op[1] = *(float4*)&o[4];
  op[2] = *(float4*)&o[8];
  op[3] = *(float4*)&o[12];
}

// ---------------- reduce + self-loop + b2 + relu + MLP head ----------------
__global__ __launch_bounds__(256) void redL2_k(
    const float* __restrict__ partial, const float* __restrict__ h,
    const float* __restrict__ dinv, const float* __restrict__ b2,
    const float* __restrict__ l1w, const float* __restrict__ l1b,
    const float* __restrict__ l2w, const float* __restrict__ l2b,
    float* __restrict__ out) {
  __shared__ float w1[256];
  __shared__ float bb[16], bb1[16], w2s[16];
  __shared__ float bb2;
  const int r = blockIdx.x, tid = threadIdx.x;
  w1[tid] = l1w[tid];
  if (tid < 16) bb[tid] = b2[tid];
  if (tid >= 16 && tid < 32) bb1[tid - 16] = l1b[tid - 16];
  if (tid >= 32 && tid < 48) w2s[tid - 32] = l2w[tid - 32];
  if (tid == 48) bb2 = l2b[0];
  __syncthreads();
  float sum[16];
#pragma unroll
  for (int c = 0; c < 16; c++) sum[c] = 0.f;
#pragma unroll
  for (int p = 0; p < P; p++) {
    float pv[16];
    load_row(partial, (p * NR + r) * 256 + tid, pv);
#pragma unroll
    for (int c = 0; c < 16; c++) sum[c] += pv[c];
  }
  const int i = r * 256 + tid;
  if (i >= NNODES) return;
  float di = dinv[i], d2 = di * di;
  float hv[16];
  load_row(h, i, hv);
  float a[16];
#pragma unroll
  for (int c = 0; c < 16; c++)
    a[c] = fmaxf(fmaf(di, sum[c], fmaf(d2, hv[c], bb[c])), 0.f);
  float o = bb2;
#pragma unroll
  for (int j = 0; j < 16; j++) {
    float s = bb1[j];
#pragma unroll
    for (int k = 0; k < 16; k++) s = fmaf(a[k], w1[k * 16 + j], s);
    o = fmaf(fmaxf(s, 0.f), w2s[j], o);
  }
  out[i] = o;
}

extern "C" void kernel_launch(void* const* d_in, const int* in_sizes, int n_in,
                              void* d_out, int out_size, void* d_ws, size_t ws_size,
                              hipStream_t stream) {
  const float* x   = (const float*)d_in[0];
  const int*   ei  = (const int*)d_in[1];
  const float* W1  = (const float*)d_in[2];
  const float* b1  = (const float*)d_in[3];
  const float* W2  = (const float*)d_in[4];
  const float* b2  = (const float*)d_in[5];
  const float* l1w = (const float*)d_in[6];
  const float* l1b = (const float*)d_in[7];
  const float* l2w = (const float*)d_in[8];
  const float* l2b = (const float*)d_in[9];
  float* out = (float*)d_out;

  char* ws = (char*)d_ws;
  size_t off = 0;
  auto alloc = [&](size_t bytes) {
    size_t o = off;
    off += (bytes + 255) & ~(size_t)255;
    return o;
  };
  int*          gcur    = (int*)(ws + alloc((size_t)NR * 4));
  float*        dinv    = (float*)(ws + alloc((size_t)NNODES * 4));
  unsigned int* ebuf    = (unsigned int*)(ws + alloc((size_t)NR * BSLOT * 4));
  float*        buf0    = (float*)(ws + alloc((size_t)NNODES * 16 * 4));
  float*        buf1    = (float*)(ws + alloc((size_t)NNODES * 16 * 4));
  float*        partial = (float*)(ws + alloc((size_t)P * NR * 256 * 16 * 4));

  const int* srcv = ei;
  const int* dstv = ei + NEDGES;
  const int NB_N = (NNODES + 255) / 256;  // 391

  hipMemsetAsync(gcur, 0, (size_t)NR * 4, stream);
  sortbin_k<<<NCHUNK, 512, 0, stream>>>(srcv, dstv, gcur, ebuf);
  deg_k<<<NR, 256, 0, stream>>>(gcur, ebuf, dinv);
  gemm1_k<<<NB_N, 256, 0, stream>>>(x, W1, buf0);
  aggP_k<<<NR * P, 256, 0, stream>>>(buf0, gcur, ebuf, dinv, partial);
  redL1_k<<<NR, 256, 0, stream>>>(partial, buf0, dinv, b1, W2, buf1);
  aggP_k<<<NR * P, 256, 0, stream>>>(buf1, gcur, ebuf, dinv, partial);
  redL2_k<<<NR, 256, 0, stream>>>(partial, buf1, dinv, b2,
                                  l1w, l1b, l2w, l2b, out);
}

// Round 14
// 260.680 us; speedup vs baseline: 4.3412x; 2.9655x over previous
//
#include <hip/hip_runtime.h>
#include <hip/hip_bf16.h>

// GCN on MI355X. R13 post-mortem: LDS f32 atomics were the wall (51.2M ops
// /agg = 200K/CU at ~3.5cy/op = 292us; occupancy 13%->38% moved time only
// 345->298us). R14: zero-atomic aggregation:
//  - prescale hs[i] = dinv[i]*h[i]  =>  agg = dinv[i]*(sum_s hs[s] + hs[i]) + b
//    (pure sum, no per-edge weight load)
//  - per-range kernel: counting-sort edges into LDS (by dst-local), then
//    node-per-quad pull with REGISTER accumulation (deg = 32+-6, balanced),
//    fused epilogue (relu+bias+W2 | relu+bias+MLP). partial/red kernels gone.

#define NNODES 100000
#define NEDGES 3200000
#define NR 391           // ceil(100000/256): 256-node dst ranges
#define BSLOT 9216       // per-range edge buffer (mean 8192, +11 sigma)
#define CHUNK 8192       // edges per sort block
#define NCHUNK ((NEDGES + CHUNK - 1) / CHUNK)  // 391

// ---------------- chunked counting-sort binning (unchanged from R8) ----------
__global__ __launch_bounds__(512) void sortbin_k(
    const int* __restrict__ src, const int* __restrict__ dst,
    int* __restrict__ gcur, unsigned int* __restrict__ ebuf) {
  __shared__ unsigned int stage[CHUNK];             // 32 KB
  __shared__ int cnt[NR], off0[NR], cur[NR], gb[NR];
  __shared__ int sc[512];
  const int tid = threadIdx.x;
  const int e0 = blockIdx.x * CHUNK;
  const int n = min(CHUNK, NEDGES - e0);
  for (int k = tid; k < NR; k += 512) cnt[k] = 0;
  __syncthreads();
  for (int k = tid; k < n; k += 512)
    atomicAdd(&cnt[dst[e0 + k] >> 8], 1);
  __syncthreads();
  sc[tid] = (tid < NR) ? cnt[tid] : 0;
  __syncthreads();
  for (int o = 1; o < 512; o <<= 1) {
    int x = (tid >= o) ? sc[tid - o] : 0;
    __syncthreads();
    sc[tid] += x;
    __syncthreads();
  }
  if (tid < NR) {
    int e = sc[tid] - cnt[tid];
    off0[tid] = e;
    cur[tid] = e;
    gb[tid] = (cnt[tid] > 0) ? atomicAdd(&gcur[tid], cnt[tid]) : 0;
  }
  __syncthreads();
  for (int k = tid; k < n; k += 512) {
    int s = src[e0 + k], d = dst[e0 + k];
    unsigned int pk = ((unsigned int)s << 8) | (unsigned int)(d & 255);
    int p = atomicAdd(&cur[d >> 8], 1);
    stage[p] = pk;
  }
  __syncthreads();
  const int wid = tid >> 6, lane = tid & 63;
  for (int r = wid; r < NR; r += 8) {
    int m = cnt[r];
    if (m == 0) continue;
    unsigned int* dp = ebuf + (size_t)r * BSLOT + gb[r];
    const unsigned int* sp = &stage[off0[r]];
    for (int k = lane; k < m; k += 64) dp[k] = sp[k];
  }
}

// ---------------- degree -> dinv ----------------
__global__ __launch_bounds__(256) void deg_k(
    const int* __restrict__ gcur, const unsigned int* __restrict__ ebuf,
    float* __restrict__ dinv) {
  __shared__ int cnt[256];
  const int r = blockIdx.x, tid = threadIdx.x;
  cnt[tid] = 0;
  __syncthreads();
  const int n = gcur[r];
  const unsigned int* bp = ebuf + (size_t)r * BSLOT;
  for (int k = tid; k < n; k += 256) atomicAdd(&cnt[bp[k] & 255u], 1);
  __syncthreads();
  int i = r * 256 + tid;
  if (i < NNODES) dinv[i] = rsqrtf((float)cnt[tid] + 1.0f);
}

// ---------------- buf0 = dinv[i] * (x @ W1)  (pre-scaled) ----------------
__global__ __launch_bounds__(256) void gemm1_k(const float* __restrict__ x,
                                               const float* __restrict__ W,
                                               const float* __restrict__ dinv,
                                               float* __restrict__ out) {
  __shared__ float w[2048];
  for (int j = threadIdx.x; j < 2048; j += 256) w[j] = W[j];
  __syncthreads();
  int i = blockIdx.x * 256 + threadIdx.x;
  if (i >= NNODES) return;
  float acc[16];
#pragma unroll
  for (int c = 0; c < 16; c++) acc[c] = 0.f;
  const float4* xr = (const float4*)(x + (size_t)i * 128);
#pragma unroll 8
  for (int k4 = 0; k4 < 32; k4++) {
    float4 xv = xr[k4];
    const float* wr = &w[k4 * 64];
#pragma unroll
    for (int c = 0; c < 16; c++)
      acc[c] = fmaf(xv.x, wr[c],
               fmaf(xv.y, wr[16 + c],
               fmaf(xv.z, wr[32 + c],
               fmaf(xv.w, wr[48 + c], acc[c]))));
  }
  float dv = dinv[i];
#pragma unroll
  for (int c = 0; c < 16; c++) acc[c] *= dv;
  float4* op = (float4*)(out + (size_t)i * 16);
  op[0] = make_float4(acc[0], acc[1], acc[2], acc[3]);
  op[1] = make_float4(acc[4], acc[5], acc[6], acc[7]);
  op[2] = make_float4(acc[8], acc[9], acc[10], acc[11]);
  op[3] = make_float4(acc[12], acc[13], acc[14], acc[15]);
}

__device__ __forceinline__ void load_row(const float* __restrict__ h, int s,
                                         float v[16]) {
  const float4* hr = (const float4*)(h + (size_t)s * 16);
  *(float4*)&v[0]  = hr[0];
  *(float4*)&v[4]  = hr[1];
  *(float4*)&v[8]  = hr[2];
  *(float4*)&v[12] = hr[3];
}

// Phases A-C shared by both agg kernels:
// A: counting-sort the range's edges into LDS slist (src ids, dst-local order)
// B: node-per-quad register-accumulated neighbor sum of pre-scaled hs rows
// C: park per-quad partial rows in amat (stride 20 floats, 16B aligned)
__device__ __forceinline__ void agg_phases(
    const float* __restrict__ hs, int n, const unsigned int* __restrict__ bp,
    int* cnt, int* rs, int* cur, int* sc, unsigned int* slist, float* amat,
    int tid) {
  cnt[tid] = 0;
  __syncthreads();
  for (int k = tid; k < n; k += 256) atomicAdd(&cnt[bp[k] & 255u], 1);
  __syncthreads();
  sc[tid] = cnt[tid];
  __syncthreads();
  for (int o = 1; o < 256; o <<= 1) {
    int x = (tid >= o) ? sc[tid - o] : 0;
    __syncthreads();
    sc[tid] += x;
    __syncthreads();
  }
  rs[tid] = sc[tid] - cnt[tid];
  cur[tid] = rs[tid];
  __syncthreads();
  for (int k = tid; k < n; k += 256) {
    unsigned int pk = bp[k];
    int p = atomicAdd(&cur[pk & 255u], 1);
    slist[p] = pk >> 8;
  }
  __syncthreads();
  const int q = tid >> 2, c4 = tid & 3;
  const size_t coff = (size_t)c4 * 4;
#pragma unroll
  for (int nn = 0; nn < 4; nn++) {
    int il = q + nn * 64;
    int base = rs[il], dg = cnt[il];
    float4 acc = make_float4(0.f, 0.f, 0.f, 0.f);
    int j = 0;
    for (; j + 4 <= dg; j += 4) {
      int s0 = slist[base + j];
      int s1 = slist[base + j + 1];
      int s2 = slist[base + j + 2];
      int s3 = slist[base + j + 3];
      float4 v0 = *(const float4*)(hs + (size_t)s0 * 16 + coff);
      float4 v1 = *(const float4*)(hs + (size_t)s1 * 16 + coff);
      float4 v2 = *(const float4*)(hs + (size_t)s2 * 16 + coff);
      float4 v3 = *(const float4*)(hs + (size_t)s3 * 16 + coff);
      acc.x += (v0.x + v1.x) + (v2.x + v3.x);
      acc.y += (v0.y + v1.y) + (v2.y + v3.y);
      acc.z += (v0.z + v1.z) + (v2.z + v3.z);
      acc.w += (v0.w + v1.w) + (v2.w + v3.w);
    }
    for (; j < dg; j++) {
      int s0 = slist[base + j];
      float4 v0 = *(const float4*)(hs + (size_t)s0 * 16 + coff);
      acc.x += v0.x; acc.y += v0.y; acc.z += v0.z; acc.w += v0.w;
    }
    *(float4*)&amat[il * 20 + c4 * 4] = acc;
  }
  __syncthreads();
}

// ---------------- layer 1: agg + b1 + relu + @W2, write dinv-prescaled ------
__global__ __launch_bounds__(256) void aggE1_k(
    const float* __restrict__ hs, const int* __restrict__ gcur,
    const unsigned int* __restrict__ ebuf, const float* __restrict__ dinv,
    const float* __restrict__ b1, const float* __restrict__ W2,
    float* __restrict__ outb) {
  __shared__ int cnt[256], rs[256], cur[256], sc[256];
  __shared__ unsigned int slist[BSLOT];     // 36.9 KB
  __shared__ float amat[256 * 20];          // 20.5 KB
  __shared__ float w2[256];
  __shared__ float bb[16];
  const int tid = threadIdx.x, r = blockIdx.x;
  w2[tid] = W2[tid];
  if (tid < 16) bb[tid] = b1[tid];
  agg_phases(hs, gcur[r], ebuf + (size_t)r * BSLOT,
             cnt, rs, cur, sc, slist, amat, tid);
  const int i = r * 256 + tid;
  if (i >= NNODES) return;
  float di = dinv[i];
  float sv[16];
  load_row(hs, i, sv);                      // self term (pre-scaled row)
  float a[16];
#pragma unroll
  for (int c = 0; c < 16; c++) {
    float s = amat[tid * 20 + c] + sv[c];
    a[c] = fmaxf(fmaf(di, s, bb[c]), 0.f);
  }
  float o[16];
#pragma unroll
  for (int c = 0; c < 16; c++) o[c] = 0.f;
#pragma unroll
  for (int k = 0; k < 16; k++) {
    float ak = a[k];
#pragma unroll
    for (int c = 0; c < 16; c++) o[c] = fmaf(ak, w2[k * 16 + c], o[c]);
  }
#pragma unroll
  for (int c = 0; c < 16; c++) o[c] *= di;  // pre-scale for layer 2
  float4* op = (float4*)(outb + (size_t)i * 16);
  op[0] = *(float4*)&o[0];
  op[1] = *(float4*)&o[4];
  op[2] = *(float4*)&o[8];
  op[3] = *(float4*)&o[12];
}

// ---------------- layer 2: agg + b2 + relu + MLP head ----------------
__global__ __launch_bounds__(256) void aggE2_k(
    const float* __restrict__ hs, const int* __restrict__ gcur,
    const unsigned int* __restrict__ ebuf, const float* __restrict__ dinv,
    const float* __restrict__ b2, const float* __restrict__ l1w,
    const float* __restrict__ l1b, const float* __restrict__ l2w,
    const float* __restrict__ l2b, float* __restrict__ out) {
  __shared__ int cnt[256], rs[256], cur[256], sc[256];
  __shared__ unsigned int slist[BSLOT];
  __shared__ float amat[256 * 20];
  __shared__ float w1[256];
  __shared__ float bb[16], bb1[16], w2s[16];
  __shared__ float bb2;
  const int tid = threadIdx.x, r = blockIdx.x;
  w1[tid] = l1w[tid];
  if (tid < 16) bb[tid] = b2[tid];
  if (tid >= 16 && tid < 32) bb1[tid - 16] = l1b[tid - 16];
  if (tid >= 32 && tid < 48) w2s[tid - 32] = l2w[tid - 32];
  if (tid == 48) bb2 = l2b[0];
  agg_phases(hs, gcur[r], ebuf + (size_t)r * BSLOT,
             cnt, rs, cur, sc, slist, amat, tid);
  const int i = r * 256 + tid;
  if (i >= NNODES) return;
  float di = dinv[i];
  float sv[16];
  load_row(hs, i, sv);
  float a[16];
#pragma unroll
  for (int c = 0; c < 16; c++) {
    float s = amat[tid * 20 + c] + sv[c];
    a[c] = fmaxf(fmaf(di, s, bb[c]), 0.f);
  }
  float o = bb2;
#pragma unroll
  for (int j = 0; j < 16; j++) {
    float s = bb1[j];
#pragma unroll
    for (int k = 0; k < 16; k++) s = fmaf(a[k], w1[k * 16 + j], s);
    o = fmaf(fmaxf(s, 0.f), w2s[j], o);
  }
  out[i] = o;
}

extern "C" void kernel_launch(void* const* d_in, const int* in_sizes, int n_in,
                              void* d_out, int out_size, void* d_ws, size_t ws_size,
                              hipStream_t stream) {
  const float* x   = (const float*)d_in[0];
  const int*   ei  = (const int*)d_in[1];
  const float* W1  = (const float*)d_in[2];
  const float* b1  = (const float*)d_in[3];
  const float* W2  = (const float*)d_in[4];
  const float* b2  = (const float*)d_in[5];
  const float* l1w = (const float*)d_in[6];
  const float* l1b = (const float*)d_in[7];
  const float* l2w = (const float*)d_in[8];
  const float* l2b = (const float*)d_in[9];
  float* out = (float*)d_out;

  char* ws = (char*)d_ws;
  size_t off = 0;
  auto alloc = [&](size_t bytes) {
    size_t o = off;
    off += (bytes + 255) & ~(size_t)255;
    return o;
  };
  int*          gcur = (int*)(ws + alloc((size_t)NR * 4));
  float*        dinv = (float*)(ws + alloc((size_t)NNODES * 4));
  unsigned int* ebuf = (unsigned int*)(ws + alloc((size_t)NR * BSLOT * 4));
  float*        buf0 = (float*)(ws + alloc((size_t)NNODES * 16 * 4));
  float*        buf1 = (float*)(ws + alloc((size_t)NNODES * 16 * 4));

  const int* srcv = ei;
  const int* dstv = ei + NEDGES;
  const int NB_N = (NNODES + 255) / 256;  // 391

  hipMemsetAsync(gcur, 0, (size_t)NR * 4, stream);
  sortbin_k<<<NCHUNK, 512, 0, stream>>>(srcv, dstv, gcur, ebuf);
  deg_k<<<NR, 256, 0, stream>>>(gcur, ebuf, dinv);
  gemm1_k<<<NB_N, 256, 0, stream>>>(x, W1, dinv, buf0);
  aggE1_k<<<NR, 256, 0, stream>>>(buf0, gcur, ebuf, dinv, b1, W2, buf1);
  aggE2_k<<<NR, 256, 0, stream>>>(buf1, gcur, ebuf, dinv, b2,
                                  l1w, l1b, l2w, l2b, out);
}